// Round 1
// baseline (431.456 us; speedup 1.0000x reference)
//
#include <hip/hip_runtime.h>
#include <stdint.h>

// Problem constants (fixed by setup_inputs): x[4096,256] f32, keys[65536,256] f32,
// values[65536,10] f32, k=8 (d_in[3], always 8 -> hardcoded).
#define B_ROWS 4096
#define N_KEYS 65536
#define DDIM 256
#define NCH 10

#define NSPLIT 8
#define SPLIT_KEYS (N_KEYS / NSPLIT)       // 8192
#define ROWS_PER_BLK 128
#define CHUNK_KEYS 128
#define NCHUNK (SPLIT_KEYS / CHUNK_KEYS)   // 64
#define NSTREAM 8                           // candidate streams per (row, split)

typedef float f32x4 __attribute__((ext_vector_type(4)));
typedef short bf16x8 __attribute__((ext_vector_type(8)));

static __device__ __forceinline__ unsigned short f2bf(float f) {
  // round-to-nearest-even fp32 -> bf16
  unsigned u = __float_as_uint(f);
  return (unsigned short)((u + 0x7FFFu + ((u >> 16) & 1u)) >> 16);
}

// order-preserving float -> uint transform (works for negatives too)
static __device__ __forceinline__ unsigned ford(float f) {
  unsigned u = __float_as_uint(f);
  return u ^ ((unsigned)((int)u >> 31) | 0x80000000u);
}
static __device__ __forceinline__ float ford_inv(unsigned u) {
  unsigned m = 0x80000000u | ((u >> 31) - 1u); // top bit set -> 0x80000000 else 0xFFFFFFFF
  return __uint_as_float(u ^ m);
}

static __device__ __forceinline__ unsigned long long shfl_xor_u64(unsigned long long v, int m) {
  unsigned lo = __shfl_xor((unsigned)v, m, 64);
  unsigned hi = __shfl_xor((unsigned)(v >> 32), m, 64);
  return ((unsigned long long)hi << 32) | lo;
}
static __device__ __forceinline__ double shfl_xor_f64(double v, int m) {
  return __longlong_as_double((long long)shfl_xor_u64((unsigned long long)__double_as_longlong(v), m));
}

// ---------------------------------------------------------------------------
// Kernel 0: per-key squared norm (fp32) + bf16 conversion of keys, written to
// global ws PRE-SWIZZLED (T2-style XOR on 16B units within each 512B row), so
// kernel A can stage chunks into LDS with a plain linear copy and still get
// conflict-free ds_read_b128 A-fragment reads.
// One wave per key. grid = N_KEYS/4 blocks of 256 threads.
// ---------------------------------------------------------------------------
__global__ void prep_keys(const float* __restrict__ keys,
                          unsigned long long* __restrict__ kbf,
                          float* __restrict__ ksq) {
  int key = blockIdx.x * 4 + (threadIdx.x >> 6);
  int lane = threadIdx.x & 63;
  const float* kr = keys + (size_t)key * DDIM;
  float4 v = *(const float4*)(kr + lane * 4);
  float ss = v.x * v.x + v.y * v.y + v.z * v.z + v.w * v.w;
#pragma unroll
  for (int off = 32; off; off >>= 1) ss += __shfl_xor(ss, off, 64);
  if (lane == 0) ksq[key] = ss;

  unsigned long long p = (unsigned long long)f2bf(v.x)
                       | ((unsigned long long)f2bf(v.y) << 16)
                       | ((unsigned long long)f2bf(v.z) << 32)
                       | ((unsigned long long)f2bf(v.w) << 48);
  // this lane's 4 bf16 = 8 bytes; 16B unit index = lane>>1, swizzled by key&7
  size_t baddr = (size_t)key * 512
               + (size_t)((((lane >> 1) ^ (key & 7)) << 4) + ((lane & 1) << 3));
  *(unsigned long long*)((char*)kbf + baddr) = p;
}

// ---------------------------------------------------------------------------
// Kernel A: fused bf16-MFMA score GEMM + per-stream top-8 candidate selection.
// Block = 1024 threads (16 waves = 2 key-halves x 8 row-tiles), covers
// 128 rows x one key split (8192 keys) in 64 chunks of 128 keys.
// score = ||key||^2 - 2*dot (row-constant ||x||^2 dropped: rank-invariant).
// Per-thread u64 heap keeps the 8 best (packed ordered-score|idx) of its
// fixed 16-keys/chunk stream; 8 streams per row -> pigeonhole guarantees the
// true global top-8 of each row is among the 64 dumped candidates per split.
// ---------------------------------------------------------------------------
__global__ __launch_bounds__(1024) void knn_main(
    const float* __restrict__ x,
    const unsigned char* __restrict__ kbf,  // pre-swizzled bf16 keys
    const float* __restrict__ ksq,
    unsigned long long* __restrict__ cand) {
  __shared__ __align__(16) unsigned char kt[CHUNK_KEYS * 512]; // 64KB: key tile, then score scratch

  const int t = threadIdx.x;
  const int lane = t & 63;
  const int wv = t >> 6;         // 0..15
  const int mw = wv & 1;         // key half (0/1) -> 64 keys each
  const int nt = wv >> 1;        // row tile 0..7 (16 rows each)
  const int lo4 = lane & 15;
  const int hi = lane >> 4;      // 0..3 (k-octet / D-row quad)

  const int split = blockIdx.x & (NSPLIT - 1);
  const int rb = (blockIdx.x >> 3) * ROWS_PER_BLK;
  const int sb = split * SPLIT_KEYS;

  // ---- load this thread's B (x) fragments for all 8 k-steps into registers
  const int xrow = rb + nt * 16 + lo4;
  const float* xr = x + (size_t)xrow * DDIM;
  bf16x8 xb[8];
#pragma unroll
  for (int s = 0; s < 8; ++s) {
    const float* p = xr + s * 32 + hi * 8;
    float4 a = *(const float4*)(p);
    float4 b = *(const float4*)(p + 4);
    union { unsigned short us[8]; bf16x8 v; } u;
    u.us[0] = f2bf(a.x); u.us[1] = f2bf(a.y); u.us[2] = f2bf(a.z); u.us[3] = f2bf(a.w);
    u.us[4] = f2bf(b.x); u.us[5] = f2bf(b.y); u.us[6] = f2bf(b.z); u.us[7] = f2bf(b.w);
    xb[s] = u.v;
  }

  unsigned long long heap[8]; // ascending; heap[7] = current 8th best
#pragma unroll
  for (int i = 0; i < 8; ++i) heap[i] = ~0ULL;
  float t8f = __uint_as_float(0x7F7FFFFFu); // +FLT_MAX guard

  for (int c = 0; c < NCHUNK; ++c) {
    const int keybase = sb + c * CHUNK_KEYS;
    __syncthreads(); // prev chunk's scratch reads / frag reads done
    // ---- stage 64KB of pre-swizzled bf16 keys (linear copy)
    {
      const uint4* src = (const uint4*)(kbf + (size_t)keybase * 512);
      uint4* dst = (uint4*)kt;
#pragma unroll
      for (int i = 0; i < 4; ++i) dst[t + i * 1024] = src[t + i * 1024];
    }
    __syncthreads();

    // ---- MFMA: dot[key][xrow] for this wave's 64 keys x 16 rows
    f32x4 acc[4];
#pragma unroll
    for (int f = 0; f < 4; ++f) acc[f] = 0.0f;
#pragma unroll
    for (int s = 0; s < 8; ++s) {
#pragma unroll
      for (int f = 0; f < 4; ++f) {
        int keyloc = mw * 64 + f * 16 + lo4;
        int off = keyloc * 512 + ((((s * 4 + hi) ^ (lo4 & 7))) << 4);
        bf16x8 af = *(const bf16x8*)(kt + off);
        acc[f] = __builtin_amdgcn_mfma_f32_16x16x32_bf16(af, xb[s], acc[f], 0, 0, 0);
      }
    }

    __syncthreads(); // all waves done reading key tile; reuse kt as score scratch

    // ---- selection: flag passing elements, batch-drain inserts
    unsigned mask = 0;
#pragma unroll
    for (int f = 0; f < 4; ++f) {
#pragma unroll
      for (int i = 0; i < 4; ++i) {
        int e = f * 4 + i;
        int kg = keybase + mw * 64 + f * 16 + hi * 4 + i; // D row -> key index
        float sc = fmaf(-2.0f, acc[f][i], ksq[kg]);
        if (sc <= t8f) {
          mask |= 1u << e;
          *(float*)(kt + (e << 12) + (t << 2)) = sc; // SoA scratch: conflict-free
        }
      }
    }
    while (__any(mask != 0)) {
      if (mask) {
        int e = __ffs(mask) - 1;
        mask &= mask - 1;
        float sc = *(const float*)(kt + (e << 12) + (t << 2));
        int kg = keybase + mw * 64 + ((e >> 2) << 4) + hi * 4 + (e & 3);
        unsigned long long v = ((unsigned long long)ford(sc) << 32) | (unsigned)kg;
        if (v < heap[7]) {
          // branchless sorted insert (descending scan keeps old heap[j-1])
#pragma unroll
          for (int j = 7; j >= 1; --j) {
            unsigned long long a = heap[j - 1];
            unsigned long long mx = a > v ? a : v;
            heap[j] = (v < heap[j]) ? mx : heap[j];
          }
          heap[0] = heap[0] < v ? heap[0] : v;
          t8f = ford_inv((unsigned)(heap[7] >> 32));
        }
      }
    }
  }

  // ---- dump this stream's top-8 candidates
  const int stream = mw * 4 + hi;
  size_t co = (((size_t)xrow * NSPLIT + split) * NSTREAM + stream) * 8;
#pragma unroll
  for (int j = 0; j < 8; ++j) cand[co + j] = heap[j];
}

// ---------------------------------------------------------------------------
// Kernel B: per row (one wave): reduce 512 candidates -> top-16 by packed
// bf16-score, recompute those 16 distances exactly in fp64, pick the true
// top-8 (tie-break by index, matching lax.top_k), average values.
// ---------------------------------------------------------------------------
__global__ void knn_refine(const float* __restrict__ x,
                           const float* __restrict__ keys,
                           const float* __restrict__ values,
                           const unsigned long long* __restrict__ cand,
                           float* __restrict__ out) {
  const int row = blockIdx.x;
  const int lane = threadIdx.x; // 64

  unsigned long long c[8];
  const unsigned long long* cr = cand + (size_t)row * (NSPLIT * NSTREAM * 8);
#pragma unroll
  for (int i = 0; i < 8; ++i) c[i] = cr[lane * 8 + i];

  const int g = lane >> 2, sub = lane & 3; // 16 groups of 4 lanes
  int idxg = 0;

#pragma unroll
  for (int r = 0; r < 16; ++r) {
    unsigned long long m = c[0];
#pragma unroll
    for (int i = 1; i < 8; ++i) m = c[i] < m ? c[i] : m;
#pragma unroll
    for (int off = 32; off; off >>= 1) {
      unsigned long long o = shfl_xor_u64(m, off);
      m = o < m ? o : m;
    }
    if (g == r) idxg = (int)(m & 0xFFFFFFFFu); // group r adopts candidate r
#pragma unroll
    for (int i = 0; i < 8; ++i)
      if (c[i] == m) c[i] = ~0ULL; // remove (values distinct: idx in low bits)
  }

  // exact fp64 squared distance of candidate g (4 lanes x 64 dims)
  const float* xr = x + (size_t)row * DDIM;
  const float* kr = keys + (size_t)idxg * DDIM;
  double s = 0.0;
#pragma unroll
  for (int d = 0; d < 64; d += 4) {
    int dd = sub * 64 + d;
    float4 xa = *(const float4*)(xr + dd);
    float4 ka = *(const float4*)(kr + dd);
    double d0 = (double)xa.x - (double)ka.x;
    double d1 = (double)xa.y - (double)ka.y;
    double d2 = (double)xa.z - (double)ka.z;
    double d3 = (double)xa.w - (double)ka.w;
    s += d0 * d0 + d1 * d1 + d2 * d2 + d3 * d3;
  }
  s += shfl_xor_f64(s, 1);
  s += shfl_xor_f64(s, 2);

  double dv = (sub == 0) ? s : 1e300;
  int di = idxg;
  int chosen[8];
#pragma unroll
  for (int r = 0; r < 8; ++r) {
    double m = dv; int mi = di;
#pragma unroll
    for (int off = 32; off; off >>= 1) {
      double om = shfl_xor_f64(m, off);
      int omi = __shfl_xor(mi, off, 64);
      if (om < m || (om == m && omi < mi)) { m = om; mi = omi; }
    }
    chosen[r] = mi;
    if (sub == 0 && di == mi) dv = 1e300; // remove winner
  }

  if (lane < NCH) {
    double a = 0.0;
#pragma unroll
    for (int r = 0; r < 8; ++r) a += (double)values[(size_t)chosen[r] * NCH + lane];
    out[row * NCH + lane] = (float)(a * 0.125);
  }
}

// ---------------------------------------------------------------------------
extern "C" void kernel_launch(void* const* d_in, const int* in_sizes, int n_in,
                              void* d_out, int out_size, void* d_ws, size_t ws_size,
                              hipStream_t stream) {
  (void)in_sizes; (void)n_in; (void)out_size; (void)ws_size;
  const float* x      = (const float*)d_in[0];
  const float* keys   = (const float*)d_in[1];
  const float* values = (const float*)d_in[2];
  // d_in[3] is k; fixed at 8 for this problem (device scalar; cannot sync-read).
  float* out = (float*)d_out;

  char* ws = (char*)d_ws;
  unsigned long long* kbf = (unsigned long long*)ws;                 // 32 MB swizzled bf16 keys
  float* ksq = (float*)(ws + (size_t)N_KEYS * 512);                  // 256 KB
  unsigned long long* cand =
      (unsigned long long*)(ws + (size_t)N_KEYS * 512 + (size_t)N_KEYS * 4); // 16 MB

  prep_keys<<<N_KEYS / 4, 256, 0, stream>>>(keys, kbf, ksq);
  knn_main<<<(B_ROWS / ROWS_PER_BLK) * NSPLIT, 1024, 0, stream>>>(
      x, (const unsigned char*)kbf, ksq, cand);
  knn_refine<<<B_ROWS, 64, 0, stream>>>(x, keys, values, cand, out);
}

// Round 2
// 390.102 us; speedup vs baseline: 1.1060x; 1.1060x over previous
//
#include <hip/hip_runtime.h>
#include <stdint.h>

// x[4096,256] f32, keys[65536,256] f32, values[65536,10] f32, k=8 (hardcoded).
#define B_ROWS 4096
#define N_KEYS 65536
#define DDIM 256
#define NCH 10

#define NSPLIT 8
#define SPLIT_KEYS (N_KEYS / NSPLIT)       // 8192
#define ROWS_PER_BLK 128
#define CHUNK_KEYS 128
#define NCHUNK (SPLIT_KEYS / CHUNK_KEYS)   // 64
#define NSTREAM 8

typedef float f32x4 __attribute__((ext_vector_type(4)));
typedef short bf16x8 __attribute__((ext_vector_type(8)));

static __device__ __forceinline__ unsigned short f2bf(float f) {
  unsigned u = __float_as_uint(f);
  return (unsigned short)((u + 0x7FFFu + ((u >> 16) & 1u)) >> 16);
}
static __device__ __forceinline__ unsigned ford(float f) {
  unsigned u = __float_as_uint(f);
  return u ^ ((unsigned)((int)u >> 31) | 0x80000000u);
}
static __device__ __forceinline__ float ford_inv(unsigned u) {
  unsigned m = 0x80000000u | ((u >> 31) - 1u);
  return __uint_as_float(u ^ m);
}
static __device__ __forceinline__ unsigned long long shfl_xor_u64(unsigned long long v, int m) {
  unsigned lo = __shfl_xor((unsigned)v, m, 64);
  unsigned hi = __shfl_xor((unsigned)(v >> 32), m, 64);
  return ((unsigned long long)hi << 32) | lo;
}
static __device__ __forceinline__ double shfl_xor_f64(double v, int m) {
  return __longlong_as_double((long long)shfl_xor_u64((unsigned long long)__double_as_longlong(v), m));
}
static __device__ __forceinline__ void gl_lds16(const void* g, void* l) {
  __builtin_amdgcn_global_load_lds(
      (const __attribute__((address_space(1))) unsigned int*)g,
      (__attribute__((address_space(3))) unsigned int*)l, 16, 0, 0);
}

// ---------------------------------------------------------------------------
// key_norms: fp32 squared norm per key. One wave per key (4 keys / 256-thr blk).
// ---------------------------------------------------------------------------
__global__ void key_norms(const float* __restrict__ keys, float* __restrict__ ksq) {
  int key = blockIdx.x * 4 + (threadIdx.x >> 6);
  int lane = threadIdx.x & 63;
  float4 v = *(const float4*)(keys + (size_t)key * DDIM + lane * 4);
  float ss = v.x * v.x + v.y * v.y + v.z * v.z + v.w * v.w;
#pragma unroll
  for (int off = 32; off; off >>= 1) ss += __shfl_xor(ss, off, 64);
  if (lane == 0) ksq[key] = ss;
}

// ---------------------------------------------------------------------------
// transpose_keys: bf16-convert + transpose each 128-key chunk to
// [chunk][koct 0..31][key 0..127][16B] so knn_main's staging is a LINEAR copy
// and its A-frag ds_read_b128s are 256B-contiguous per 16-lane phase
// (conflict-free, no swizzle in the hot loop). 512 blocks x 256 threads.
// ---------------------------------------------------------------------------
__global__ __launch_bounds__(256) void transpose_keys(const float* __restrict__ keys,
                                                      unsigned char* __restrict__ kbf) {
  __shared__ __align__(16) unsigned char T[128 * 512]; // 64KB, XOR-swizzled units
  const int t = threadIdx.x;
  const int chunk = blockIdx.x;
  const float4* src = (const float4*)(keys + (size_t)chunk * CHUNK_KEYS * DDIM);
#pragma unroll
  for (int j = 0; j < 32; ++j) {
    int g = j * 256 + t;            // float4 index 0..8191
    float4 v = src[g];
    int key = g >> 6, rem = g & 63; // 64 float4 per key
    int u = rem >> 1, sub = rem & 1;
    unsigned lo = ((unsigned)f2bf(v.y) << 16) | f2bf(v.x);
    unsigned hi2 = ((unsigned)f2bf(v.w) << 16) | f2bf(v.z);
    unsigned long long p = ((unsigned long long)hi2 << 32) | lo;
    *(unsigned long long*)&T[key * 512 + ((u ^ (key & 7)) << 4) + (sub << 3)] = p;
  }
  __syncthreads();
  uint4* dst = (uint4*)(kbf + (size_t)chunk * 65536);
#pragma unroll
  for (int j = 0; j < 16; ++j) {
    int ou = j * 256 + t;           // out unit = koct*128 + key
    int koct = ou >> 7, key = ou & 127;
    dst[ou] = *(const uint4*)&T[key * 512 + ((koct ^ (key & 7)) << 4)];
  }
}

// ---------------------------------------------------------------------------
// knn_main: 512 threads = 8 waves = 2 key-halves x 4 row-quads(32 rows).
// Each A-frag (keys) ds_read feeds TWO MFMAs (two 16-row x register sets):
// LDS read traffic halved vs r1. Double-buffered tiles staged by
// global_load_lds(16B) prefetched one full chunk ahead; ONE barrier/chunk.
// ---------------------------------------------------------------------------
__global__ __launch_bounds__(512) void knn_main(
    const float* __restrict__ x,
    const unsigned char* __restrict__ kbf,
    const float* __restrict__ ksq,
    unsigned long long* __restrict__ cand) {
  __shared__ __align__(16) unsigned char tiles[2][65536]; // 128KB double buffer
  __shared__ float scr[8][512];                           // 16KB drain scratch

  const int t = threadIdx.x;
  const int lane = t & 63;
  const int wv = t >> 6;          // 0..7
  const int mw = wv & 1;          // key half (64 keys)
  const int ws = wv >> 1;         // row quad (32 rows)
  const int lo4 = lane & 15;
  const int hi = lane >> 4;

  const int split = blockIdx.x & (NSPLIT - 1);
  const int rb = (blockIdx.x >> 3) * ROWS_PER_BLK;

  // ---- x fragments for two 16-row sets (held in registers for whole kernel)
  const int xrow0 = rb + ws * 32 + lo4;
  const int xrow1 = xrow0 + 16;
  bf16x8 xb0[8], xb1[8];
#pragma unroll
  for (int s = 0; s < 8; ++s) {
    const float* p0 = x + (size_t)xrow0 * DDIM + s * 32 + hi * 8;
    const float* p1 = x + (size_t)xrow1 * DDIM + s * 32 + hi * 8;
    float4 a = *(const float4*)p0, b = *(const float4*)(p0 + 4);
    float4 c = *(const float4*)p1, d = *(const float4*)(p1 + 4);
    union { unsigned short us[8]; bf16x8 v; } u0, u1;
    u0.us[0]=f2bf(a.x); u0.us[1]=f2bf(a.y); u0.us[2]=f2bf(a.z); u0.us[3]=f2bf(a.w);
    u0.us[4]=f2bf(b.x); u0.us[5]=f2bf(b.y); u0.us[6]=f2bf(b.z); u0.us[7]=f2bf(b.w);
    u1.us[0]=f2bf(c.x); u1.us[1]=f2bf(c.y); u1.us[2]=f2bf(c.z); u1.us[3]=f2bf(c.w);
    u1.us[4]=f2bf(d.x); u1.us[5]=f2bf(d.y); u1.us[6]=f2bf(d.z); u1.us[7]=f2bf(d.w);
    xb0[s] = u0.v; xb1[s] = u1.v;
  }

  unsigned long long h0[8], h1[8];
#pragma unroll
  for (int i = 0; i < 8; ++i) { h0[i] = ~0ULL; h1[i] = ~0ULL; }
  float thr0 = __uint_as_float(0x7F7FFFFFu);
  float thr1 = __uint_as_float(0x7F7FFFFFu);

  const unsigned char* srcbase = kbf + ((size_t)split * NCHUNK << 16);

  // stage chunk c into buffer buf (64KB, linear: 8 x 16B per thread)
  auto STAGE = [&](int c, int buf) {
    const unsigned char* src = srcbase + ((size_t)c << 16);
    unsigned char* wb = &tiles[buf][(size_t)wv * 64 * 16];
#pragma unroll
    for (int i = 0; i < 8; ++i)
      gl_lds16(src + (((i * 512) + t) << 4), wb + ((i * 512) << 4));
  };

  STAGE(0, 0);
  __syncthreads();

#pragma unroll 1
  for (int c = 0; c < NCHUNK; ++c) {
    const int keybase = split * SPLIT_KEYS + c * CHUNK_KEYS;
    if (c + 1 < NCHUNK) STAGE(c + 1, (c + 1) & 1); // prefetch next tile

    // ---- MFMA: 64 keys x 32 rows, A-frag reused across both row sets
    const unsigned char* tile = tiles[c & 1];
    f32x4 a0[4], a1[4];
#pragma unroll
    for (int f = 0; f < 4; ++f) { a0[f] = 0.0f; a1[f] = 0.0f; }
#pragma unroll
    for (int s = 0; s < 8; ++s) {
      const unsigned char* rp = tile + (s * 4 + hi) * 2048 + (mw * 64 + lo4) * 16;
      bf16x8 af[4];
#pragma unroll
      for (int f = 0; f < 4; ++f) af[f] = *(const bf16x8*)(rp + f * 256);
#pragma unroll
      for (int f = 0; f < 4; ++f)
        a0[f] = __builtin_amdgcn_mfma_f32_16x16x32_bf16(af[f], xb0[s], a0[f], 0, 0, 0);
#pragma unroll
      for (int f = 0; f < 4; ++f)
        a1[f] = __builtin_amdgcn_mfma_f32_16x16x32_bf16(af[f], xb1[s], a1[f], 0, 0, 0);
    }

    // ---- selection (same keys for both row sets)
    float4 kq[4];
#pragma unroll
    for (int f = 0; f < 4; ++f)
      kq[f] = *(const float4*)(ksq + keybase + mw * 64 + f * 16 + hi * 4);

    auto select = [&](f32x4* a, unsigned long long* hp, float& thr) {
#pragma unroll
      for (int b = 0; b < 2; ++b) {
        unsigned m = 0;
#pragma unroll
        for (int f2 = 0; f2 < 2; ++f2) {
          int f = b * 2 + f2;
#pragma unroll
          for (int i = 0; i < 4; ++i) {
            float sc = fmaf(-2.0f, a[f][i], ((const float*)&kq[f])[i]);
            int e = f2 * 4 + i;
            if (sc <= thr) { m |= 1u << e; scr[e][t] = sc; }
          }
        }
        while (__any(m != 0)) {
          if (m) {
            int e = __ffs(m) - 1; m &= m - 1;
            float sc = scr[e][t];
            int kg = keybase + mw * 64 + (b * 2 + (e >> 2)) * 16 + hi * 4 + (e & 3);
            unsigned long long v = ((unsigned long long)ford(sc) << 32) | (unsigned)kg;
            if (v < hp[7]) {
#pragma unroll
              for (int j = 7; j >= 1; --j) {
                unsigned long long aa = hp[j - 1];
                unsigned long long mx = aa > v ? aa : v;
                hp[j] = (v < hp[j]) ? mx : hp[j];
              }
              hp[0] = hp[0] < v ? hp[0] : v;
              thr = ford_inv((unsigned)(hp[7] >> 32));
            }
          }
        }
      }
    };
    select(a0, h0, thr0);
    select(a1, h1, thr1);

    __syncthreads(); // tile consumed by all waves; prefetch drained here too
  }

  // ---- dump candidates: 8 per (row, split, stream)
  const int stream = mw * 4 + hi;
  size_t co0 = (((size_t)xrow0 * NSPLIT + split) * NSTREAM + stream) * 8;
  size_t co1 = (((size_t)xrow1 * NSPLIT + split) * NSTREAM + stream) * 8;
#pragma unroll
  for (int j = 0; j < 8; ++j) { cand[co0 + j] = h0[j]; cand[co1 + j] = h1[j]; }
}

// ---------------------------------------------------------------------------
// knn_refine: per row (one wave): 512 candidates -> top-16 by packed score,
// recompute those 16 in fp64, true top-8 (idx tiebreak), average values.
// ---------------------------------------------------------------------------
__global__ void knn_refine(const float* __restrict__ x,
                           const float* __restrict__ keys,
                           const float* __restrict__ values,
                           const unsigned long long* __restrict__ cand,
                           float* __restrict__ out) {
  const int row = blockIdx.x;
  const int lane = threadIdx.x;

  unsigned long long c[8];
  const unsigned long long* cr = cand + (size_t)row * (NSPLIT * NSTREAM * 8);
#pragma unroll
  for (int i = 0; i < 8; ++i) c[i] = cr[lane * 8 + i];

  const int g = lane >> 2, sub = lane & 3;
  int idxg = 0;

#pragma unroll
  for (int r = 0; r < 16; ++r) {
    unsigned long long m = c[0];
#pragma unroll
    for (int i = 1; i < 8; ++i) m = c[i] < m ? c[i] : m;
#pragma unroll
    for (int off = 32; off; off >>= 1) {
      unsigned long long o = shfl_xor_u64(m, off);
      m = o < m ? o : m;
    }
    if (g == r) idxg = (int)(m & 0xFFFFFFFFu);
#pragma unroll
    for (int i = 0; i < 8; ++i)
      if (c[i] == m) c[i] = ~0ULL;
  }

  const float* xr = x + (size_t)row * DDIM;
  const float* kr = keys + (size_t)idxg * DDIM;
  double s = 0.0;
#pragma unroll
  for (int d = 0; d < 64; d += 4) {
    int dd = sub * 64 + d;
    float4 xa = *(const float4*)(xr + dd);
    float4 ka = *(const float4*)(kr + dd);
    double d0 = (double)xa.x - (double)ka.x;
    double d1 = (double)xa.y - (double)ka.y;
    double d2 = (double)xa.z - (double)ka.z;
    double d3 = (double)xa.w - (double)ka.w;
    s += d0 * d0 + d1 * d1 + d2 * d2 + d3 * d3;
  }
  s += shfl_xor_f64(s, 1);
  s += shfl_xor_f64(s, 2);

  double dv = (sub == 0) ? s : 1e300;
  int di = idxg;
  int chosen[8];
#pragma unroll
  for (int r = 0; r < 8; ++r) {
    double m = dv; int mi = di;
#pragma unroll
    for (int off = 32; off; off >>= 1) {
      double om = shfl_xor_f64(m, off);
      int omi = __shfl_xor(mi, off, 64);
      if (om < m || (om == m && omi < mi)) { m = om; mi = omi; }
    }
    chosen[r] = mi;
    if (sub == 0 && di == mi) dv = 1e300;
  }

  if (lane < NCH) {
    double a = 0.0;
#pragma unroll
    for (int r = 0; r < 8; ++r) a += (double)values[(size_t)chosen[r] * NCH + lane];
    out[row * NCH + lane] = (float)(a * 0.125);
  }
}

// ---------------------------------------------------------------------------
extern "C" void kernel_launch(void* const* d_in, const int* in_sizes, int n_in,
                              void* d_out, int out_size, void* d_ws, size_t ws_size,
                              hipStream_t stream) {
  (void)in_sizes; (void)n_in; (void)out_size; (void)ws_size;
  const float* x      = (const float*)d_in[0];
  const float* keys   = (const float*)d_in[1];
  const float* values = (const float*)d_in[2];
  float* out = (float*)d_out;

  char* ws = (char*)d_ws;
  unsigned char* kbf = (unsigned char*)ws;                            // 32 MB transposed bf16 keys
  float* ksq = (float*)(ws + (size_t)N_KEYS * 512);                   // 256 KB
  unsigned long long* cand =
      (unsigned long long*)(ws + (size_t)N_KEYS * 512 + (size_t)N_KEYS * 4); // 16 MB

  key_norms<<<N_KEYS / 4, 256, 0, stream>>>(keys, ksq);
  transpose_keys<<<N_KEYS / CHUNK_KEYS, 256, 0, stream>>>(keys, kbf);
  knn_main<<<(B_ROWS / ROWS_PER_BLK) * NSPLIT, 512, 0, stream>>>(
      x, kbf, ksq, cand);
  knn_refine<<<B_ROWS, 64, 0, stream>>>(x, keys, values, cand, out);
}

// Round 3
// 372.108 us; speedup vs baseline: 1.1595x; 1.0484x over previous
//
#include <hip/hip_runtime.h>
#include <stdint.h>
#include <float.h>

// x[4096,256] f32, keys[65536,256] f32, values[65536,10] f32, k=8 (hardcoded).
#define B_ROWS 4096
#define N_KEYS 65536
#define DDIM 256
#define NCH 10

#define NSPLIT 8
#define SPLIT_KEYS (N_KEYS / NSPLIT)       // 8192
#define ROWS_PER_BLK 128
#define CHUNK_KEYS 128
#define NCHUNK (SPLIT_KEYS / CHUNK_KEYS)   // 64
#define NSTREAM 8

typedef float f32x4 __attribute__((ext_vector_type(4)));
typedef short bf16x8 __attribute__((ext_vector_type(8)));

static __device__ __forceinline__ unsigned short f2bf(float f) {
  unsigned u = __float_as_uint(f);
  return (unsigned short)((u + 0x7FFFu + ((u >> 16) & 1u)) >> 16);
}
static __device__ __forceinline__ unsigned ford(float f) {
  unsigned u = __float_as_uint(f);
  return u ^ ((unsigned)((int)u >> 31) | 0x80000000u);
}
static __device__ __forceinline__ float ford_inv(unsigned u) {
  unsigned m = 0x80000000u | ((u >> 31) - 1u);
  return __uint_as_float(u ^ m);
}
static __device__ __forceinline__ unsigned long long shfl_xor_u64(unsigned long long v, int m) {
  unsigned lo = __shfl_xor((unsigned)v, m, 64);
  unsigned hi = __shfl_xor((unsigned)(v >> 32), m, 64);
  return ((unsigned long long)hi << 32) | lo;
}
static __device__ __forceinline__ double shfl_xor_f64(double v, int m) {
  return __longlong_as_double((long long)shfl_xor_u64((unsigned long long)__double_as_longlong(v), m));
}
static __device__ __forceinline__ void gl_lds16(const void* g, void* l) {
  __builtin_amdgcn_global_load_lds(
      (const __attribute__((address_space(1))) unsigned int*)g,
      (__attribute__((address_space(3))) unsigned int*)l, 16, 0, 0);
}

// ---------------------------------------------------------------------------
// key_norms: fp32 squared norm per key. One wave per key.
// ---------------------------------------------------------------------------
__global__ void key_norms(const float* __restrict__ keys, float* __restrict__ ksq) {
  int key = blockIdx.x * 4 + (threadIdx.x >> 6);
  int lane = threadIdx.x & 63;
  float4 v = *(const float4*)(keys + (size_t)key * DDIM + lane * 4);
  float ss = v.x * v.x + v.y * v.y + v.z * v.z + v.w * v.w;
#pragma unroll
  for (int off = 32; off; off >>= 1) ss += __shfl_xor(ss, off, 64);
  if (lane == 0) ksq[key] = ss;
}

// ---------------------------------------------------------------------------
// transpose_keys: bf16-convert + transpose each 128-key chunk to
// [chunk][koct][key][16B] so knn_main staging is linear and A-frag reads are
// 256B-contiguous per 16-lane phase (conflict-free).
// ---------------------------------------------------------------------------
__global__ __launch_bounds__(256) void transpose_keys(const float* __restrict__ keys,
                                                      unsigned char* __restrict__ kbf) {
  __shared__ __align__(16) unsigned char T[128 * 512];
  const int t = threadIdx.x;
  const int chunk = blockIdx.x;
  const float4* src = (const float4*)(keys + (size_t)chunk * CHUNK_KEYS * DDIM);
#pragma unroll
  for (int j = 0; j < 32; ++j) {
    int g = j * 256 + t;
    float4 v = src[g];
    int key = g >> 6, rem = g & 63;
    int u = rem >> 1, sub = rem & 1;
    unsigned lo = ((unsigned)f2bf(v.y) << 16) | f2bf(v.x);
    unsigned hi2 = ((unsigned)f2bf(v.w) << 16) | f2bf(v.z);
    unsigned long long p = ((unsigned long long)hi2 << 32) | lo;
    *(unsigned long long*)&T[key * 512 + ((u ^ (key & 7)) << 4) + (sub << 3)] = p;
  }
  __syncthreads();
  uint4* dst = (uint4*)(kbf + (size_t)chunk * 65536);
#pragma unroll
  for (int j = 0; j < 16; ++j) {
    int ou = j * 256 + t;
    int koct = ou >> 7, key = ou & 127;
    dst[ou] = *(const uint4*)&T[key * 512 + ((koct ^ (key & 7)) << 4)];
  }
}

// ---------------------------------------------------------------------------
// knn_main: 512 thr = 8 waves = 2 key-halves x 4 row-quads (32 rows each).
// Selection is gated by thr = min(heap 8th, tau_row), where tau_row =
// max over the row's 8 streams of each stream's running MIN score.
// Validity: the 8 stream-mins are 8 distinct elements => row's true 8th-best
// v8 <= max(stream mins) = tau at all times (tau only tightens). A true
// top-8 element e always passes (sc_e <= v8 <= tau) and cannot be evicted
// from its thread heap (eviction needs 8 better same-stream elements, which
// would contradict e being in the row top-8). tau is exchanged between the
// two mw-waves via a parity-double-buffered LDS array (one chunk lag: still
// a valid upper bound; parity avoids read/write races under one barrier).
// ---------------------------------------------------------------------------
__global__ __launch_bounds__(512) void knn_main(
    const float* __restrict__ x,
    const unsigned char* __restrict__ kbf,
    const float* __restrict__ ksq,
    unsigned long long* __restrict__ cand) {
  __shared__ __align__(16) unsigned char tiles[2][65536]; // 128KB double buffer
  __shared__ float tauh[2][2][4][2][16];                  // [parity][set][ws][mw][lo4]

  const int t = threadIdx.x;
  const int lane = t & 63;
  const int wv = t >> 6;
  const int mw = wv & 1;
  const int ws = wv >> 1;
  const int lo4 = lane & 15;
  const int hi = lane >> 4;

  const int split = blockIdx.x & (NSPLIT - 1);
  const int rb = (blockIdx.x >> 3) * ROWS_PER_BLK;

  const int xrow0 = rb + ws * 32 + lo4;
  const int xrow1 = xrow0 + 16;
  bf16x8 xb0[8], xb1[8];
#pragma unroll
  for (int s = 0; s < 8; ++s) {
    const float* p0 = x + (size_t)xrow0 * DDIM + s * 32 + hi * 8;
    const float* p1 = x + (size_t)xrow1 * DDIM + s * 32 + hi * 8;
    float4 a = *(const float4*)p0, b = *(const float4*)(p0 + 4);
    float4 c = *(const float4*)p1, d = *(const float4*)(p1 + 4);
    union { unsigned short us[8]; bf16x8 v; } u0, u1;
    u0.us[0]=f2bf(a.x); u0.us[1]=f2bf(a.y); u0.us[2]=f2bf(a.z); u0.us[3]=f2bf(a.w);
    u0.us[4]=f2bf(b.x); u0.us[5]=f2bf(b.y); u0.us[6]=f2bf(b.z); u0.us[7]=f2bf(b.w);
    u1.us[0]=f2bf(c.x); u1.us[1]=f2bf(c.y); u1.us[2]=f2bf(c.z); u1.us[3]=f2bf(c.w);
    u1.us[4]=f2bf(d.x); u1.us[5]=f2bf(d.y); u1.us[6]=f2bf(d.z); u1.us[7]=f2bf(d.w);
    xb0[s] = u0.v; xb1[s] = u1.v;
  }

  unsigned long long h0[8], h1[8];
#pragma unroll
  for (int i = 0; i < 8; ++i) { h0[i] = ~0ULL; h1[i] = ~0ULL; }
  float t8f0 = FLT_MAX, t8f1 = FLT_MAX;
  float smin0 = FLT_MAX, smin1 = FLT_MAX; // running stream minima

  const unsigned char* srcbase = kbf + ((size_t)split * NCHUNK << 16);

  auto STAGE = [&](int c, int buf) {
    const unsigned char* src = srcbase + ((size_t)c << 16);
    unsigned char* wb = &tiles[buf][(size_t)wv * 64 * 16];
#pragma unroll
    for (int i = 0; i < 8; ++i)
      gl_lds16(src + (((i * 512) + t) << 4), wb + ((i * 512) << 4));
  };

  STAGE(0, 0);
  ((float*)tauh)[t] = FLT_MAX; // 512 entries, one per thread
  __syncthreads();

#pragma unroll 1
  for (int c = 0; c < NCHUNK; ++c) {
    const int keybase = split * SPLIT_KEYS + c * CHUNK_KEYS;
    if (c + 1 < NCHUNK) STAGE(c + 1, (c + 1) & 1);

    // ---- MFMA: 64 keys x 32 rows; A-frag shared by both row sets
    const unsigned char* tile = tiles[c & 1];
    f32x4 a0[4], a1[4];
#pragma unroll
    for (int f = 0; f < 4; ++f) { a0[f] = 0.0f; a1[f] = 0.0f; }
#pragma unroll
    for (int s = 0; s < 8; ++s) {
      const unsigned char* rp = tile + (s * 4 + hi) * 2048 + (mw * 64 + lo4) * 16;
      bf16x8 af[4];
#pragma unroll
      for (int f = 0; f < 4; ++f) af[f] = *(const bf16x8*)(rp + f * 256);
#pragma unroll
      for (int f = 0; f < 4; ++f)
        a0[f] = __builtin_amdgcn_mfma_f32_16x16x32_bf16(af[f], xb0[s], a0[f], 0, 0, 0);
#pragma unroll
      for (int f = 0; f < 4; ++f)
        a1[f] = __builtin_amdgcn_mfma_f32_16x16x32_bf16(af[f], xb1[s], a1[f], 0, 0, 0);
    }

    // ---- scores + gated selection
    float4 kq[4];
#pragma unroll
    for (int f = 0; f < 4; ++f)
      kq[f] = *(const float4*)(ksq + keybase + mw * 64 + f * 16 + hi * 4);

    const int par = c & 1;
    const float tau0 = fmaxf(tauh[par ^ 1][0][ws][0][lo4], tauh[par ^ 1][0][ws][1][lo4]);
    const float tau1 = fmaxf(tauh[par ^ 1][1][ws][0][lo4], tauh[par ^ 1][1][ws][1][lo4]);

    float sc0[16], sc1[16];
#pragma unroll
    for (int f = 0; f < 4; ++f)
#pragma unroll
      for (int i = 0; i < 4; ++i) {
        float kqe = ((const float*)&kq[f])[i];
        sc0[f * 4 + i] = fmaf(-2.0f, a0[f][i], kqe);
        sc1[f * 4 + i] = fmaf(-2.0f, a1[f][i], kqe);
      }
    float mb0 = sc0[0], mb1 = sc1[0];
#pragma unroll
    for (int e = 1; e < 16; ++e) { mb0 = fminf(mb0, sc0[e]); mb1 = fminf(mb1, sc1[e]); }

    auto slow = [&](const float* sc, unsigned long long* hp, float& t8, float tau) {
      float thr = fminf(t8, tau);
#pragma unroll
      for (int e = 0; e < 16; ++e) {
        if (sc[e] <= thr) {
          int kg = keybase + mw * 64 + (e >> 2) * 16 + hi * 4 + (e & 3);
          unsigned long long v = ((unsigned long long)ford(sc[e]) << 32) | (unsigned)kg;
          if (v < hp[7]) {
#pragma unroll
            for (int j = 7; j >= 1; --j) {
              unsigned long long aa = hp[j - 1];
              unsigned long long mx = aa > v ? aa : v;
              hp[j] = (v < hp[j]) ? mx : hp[j];
            }
            hp[0] = hp[0] < v ? hp[0] : v;
            t8 = ford_inv((unsigned)(hp[7] >> 32));
            thr = fminf(t8, tau);
          }
        }
      }
    };
    if (mb0 <= fminf(t8f0, tau0)) slow(sc0, h0, t8f0, tau0); // rare after warm-up
    if (mb1 <= fminf(t8f1, tau1)) slow(sc1, h1, t8f1, tau1);

    smin0 = fminf(smin0, mb0);
    smin1 = fminf(smin1, mb1);

    // ---- publish tau components (max over hi of stream mins, per mw)
    float m40 = smin0, m41 = smin1;
    m40 = fmaxf(m40, __shfl_xor(m40, 16, 64));
    m40 = fmaxf(m40, __shfl_xor(m40, 32, 64));
    m41 = fmaxf(m41, __shfl_xor(m41, 16, 64));
    m41 = fmaxf(m41, __shfl_xor(m41, 32, 64));
    if (hi == 0) {
      tauh[par][0][ws][mw][lo4] = m40;
      tauh[par][1][ws][mw][lo4] = m41;
    }

    __syncthreads(); // tile consumed; prefetch drained; tau published
  }

  const int stream = mw * 4 + hi;
  size_t co0 = (((size_t)xrow0 * NSPLIT + split) * NSTREAM + stream) * 8;
  size_t co1 = (((size_t)xrow1 * NSPLIT + split) * NSTREAM + stream) * 8;
#pragma unroll
  for (int j = 0; j < 8; ++j) { cand[co0 + j] = h0[j]; cand[co1 + j] = h1[j]; }
}

// ---------------------------------------------------------------------------
// knn_refine: per row (one wave): 512 candidates -> top-16 by packed score,
// recompute those 16 in fp64, true top-8 (idx tiebreak), average values.
// ---------------------------------------------------------------------------
__global__ void knn_refine(const float* __restrict__ x,
                           const float* __restrict__ keys,
                           const float* __restrict__ values,
                           const unsigned long long* __restrict__ cand,
                           float* __restrict__ out) {
  const int row = blockIdx.x;
  const int lane = threadIdx.x;

  unsigned long long c[8];
  const unsigned long long* cr = cand + (size_t)row * (NSPLIT * NSTREAM * 8);
#pragma unroll
  for (int i = 0; i < 8; ++i) c[i] = cr[lane * 8 + i];

  const int g = lane >> 2, sub = lane & 3;
  int idxg = 0;

#pragma unroll
  for (int r = 0; r < 16; ++r) {
    unsigned long long m = c[0];
#pragma unroll
    for (int i = 1; i < 8; ++i) m = c[i] < m ? c[i] : m;
#pragma unroll
    for (int off = 32; off; off >>= 1) {
      unsigned long long o = shfl_xor_u64(m, off);
      m = o < m ? o : m;
    }
    if (g == r) idxg = (int)(m & 0xFFFFFFFFu);
#pragma unroll
    for (int i = 0; i < 8; ++i)
      if (c[i] == m) c[i] = ~0ULL;
  }

  const float* xr = x + (size_t)row * DDIM;
  const float* kr = keys + (size_t)idxg * DDIM;
  double s = 0.0;
#pragma unroll
  for (int d = 0; d < 64; d += 4) {
    int dd = sub * 64 + d;
    float4 xa = *(const float4*)(xr + dd);
    float4 ka = *(const float4*)(kr + dd);
    double d0 = (double)xa.x - (double)ka.x;
    double d1 = (double)xa.y - (double)ka.y;
    double d2 = (double)xa.z - (double)ka.z;
    double d3 = (double)xa.w - (double)ka.w;
    s += d0 * d0 + d1 * d1 + d2 * d2 + d3 * d3;
  }
  s += shfl_xor_f64(s, 1);
  s += shfl_xor_f64(s, 2);

  double dv = (sub == 0) ? s : 1e300;
  int di = idxg;
  int chosen[8];
#pragma unroll
  for (int r = 0; r < 8; ++r) {
    double m = dv; int mi = di;
#pragma unroll
    for (int off = 32; off; off >>= 1) {
      double om = shfl_xor_f64(m, off);
      int omi = __shfl_xor(mi, off, 64);
      if (om < m || (om == m && omi < mi)) { m = om; mi = omi; }
    }
    chosen[r] = mi;
    if (sub == 0 && di == mi) dv = 1e300;
  }

  if (lane < NCH) {
    double a = 0.0;
#pragma unroll
    for (int r = 0; r < 8; ++r) a += (double)values[(size_t)chosen[r] * NCH + lane];
    out[row * NCH + lane] = (float)(a * 0.125);
  }
}

// ---------------------------------------------------------------------------
extern "C" void kernel_launch(void* const* d_in, const int* in_sizes, int n_in,
                              void* d_out, int out_size, void* d_ws, size_t ws_size,
                              hipStream_t stream) {
  (void)in_sizes; (void)n_in; (void)out_size; (void)ws_size;
  const float* x      = (const float*)d_in[0];
  const float* keys   = (const float*)d_in[1];
  const float* values = (const float*)d_in[2];
  float* out = (float*)d_out;

  char* ws = (char*)d_ws;
  unsigned char* kbf = (unsigned char*)ws;                            // 32 MB transposed bf16 keys
  float* ksq = (float*)(ws + (size_t)N_KEYS * 512);                   // 256 KB
  unsigned long long* cand =
      (unsigned long long*)(ws + (size_t)N_KEYS * 512 + (size_t)N_KEYS * 4); // 16 MB

  key_norms<<<N_KEYS / 4, 256, 0, stream>>>(keys, ksq);
  transpose_keys<<<N_KEYS / CHUNK_KEYS, 256, 0, stream>>>(keys, kbf);
  knn_main<<<(B_ROWS / ROWS_PER_BLK) * NSPLIT, 512, 0, stream>>>(
      x, kbf, ksq, cand);
  knn_refine<<<B_ROWS, 64, 0, stream>>>(x, keys, values, cand, out);
}